// Round 4
// baseline (190.063 us; speedup 1.0000x reference)
//
#include <hip/hip_runtime.h>
#include <cfloat>

typedef float f32x2 __attribute__((ext_vector_type(2)));

// CDNA4 packed-f32 VOP3P ops (2 lanes/instr, full rate) — hipcc won't form
// these reliably from scalar code, so force via inline asm.
// NOTE: gfx950 has v_pk_{fma,add,mul}_f32 but NO v_pk_max_f32.
__device__ __forceinline__ f32x2 pk_fma(f32x2 a, f32x2 b, f32x2 c) {
    f32x2 d; asm("v_pk_fma_f32 %0, %1, %2, %3" : "=v"(d) : "v"(a), "v"(b), "v"(c)); return d;
}
__device__ __forceinline__ f32x2 pk_add(f32x2 a, f32x2 b) {
    f32x2 d; asm("v_pk_add_f32 %0, %1, %2" : "=v"(d) : "v"(a), "v"(b)); return d;
}
__device__ __forceinline__ f32x2 pk_mul(f32x2 a, f32x2 b) {
    f32x2 d; asm("v_pk_mul_f32 %0, %1, %2" : "=v"(d) : "v"(a), "v"(b)); return d;
}
__device__ __forceinline__ f32x2 pk_max(f32x2 a, f32x2 b) {   // scalar pair (no pk max on gfx950)
    f32x2 d; d.x = fmaxf(a.x, b.x); d.y = fmaxf(a.y, b.y); return d;
}

template<int CTRL>
__device__ __forceinline__ float dppmov(float v) {
    return __int_as_float(__builtin_amdgcn_mov_dpp(__float_as_int(v), CTRL, 0xF, 0xF, true));
}
// all-reduce across each 16-lane group (pure VALU, DPP-fused adds)
__device__ __forceinline__ float sum16(float v) {
    v += dppmov<0xB1>(v);    // quad_perm xor1
    v += dppmov<0x4E>(v);    // quad_perm xor2
    v += dppmov<0x124>(v);   // row_ror:4
    v += dppmov<0x128>(v);   // row_ror:8
    return v;
}
__device__ __forceinline__ float max16(float v) {
    v = fmaxf(v, dppmov<0xB1>(v));
    v = fmaxf(v, dppmov<0x4E>(v));
    v = fmaxf(v, dppmov<0x124>(v));
    v = fmaxf(v, dppmov<0x128>(v));
    return v;
}

__device__ __forceinline__ f32x2 shflxor2(f32x2 v, int m) {
    f32x2 r; r.x = __shfl_xor(v.x, m); r.y = __shfl_xor(v.y, m); return r;
}

#define NIT 21
#define SMIN 1e-33f

// One 256-thread block per 128x128 matrix. Thread t owns an 8x8 tile
// (rows rg*8.., cols cg*8..). Linear-space Sinkhorn: K = 2^((x - rowmax)*S)
// fixed in registers as f32x2[8][4]; per-phase scale factors a_i, b_j via
// packed FMA sums + v_rcp. All hot elementwise math is v_pk_*_f32.
__global__ __launch_bounds__(256) void sinkhorn_kernel(const float* __restrict__ in,
                                                       float* __restrict__ out) {
    const int t  = threadIdx.x;
    const int rg = t >> 4;
    const int cg = t & 15;
    const int wv = t >> 6;
    const size_t base = (size_t)blockIdx.x * (128 * 128);
    const float* __restrict__ src = in  + base + ((size_t)rg << 10) + ((size_t)cg << 3);
    float*       __restrict__ dst = out + base + ((size_t)rg << 10) + ((size_t)cg << 3);

    const float SCALE = 36.067376022224085f;  // (1/0.04) * log2(e)
    const f32x2 S2 = {SCALE, SCALE};

    f32x2 E[8][4];
#pragma unroll
    for (int i = 0; i < 8; ++i) {
        float4 a4 = *(const float4*)(src + (i << 7));
        float4 b4 = *(const float4*)(src + (i << 7) + 4);
        E[i][0] = (f32x2){a4.x, a4.y};
        E[i][1] = (f32x2){a4.z, a4.w};
        E[i][2] = (f32x2){b4.x, b4.y};
        E[i][3] = (f32x2){b4.z, b4.w};
    }

    float a[8];
    f32x2 b[4];

    // ---- row phase 1 fused with exponentiation: E = 2^((x - rowmax)*S), a_i = 1/rowsum ----
#pragma unroll
    for (int i = 0; i < 8; ++i) {
        f32x2 m2 = pk_max(pk_max(E[i][0], E[i][1]), pk_max(E[i][2], E[i][3]));
        float m = fmaxf(m2.x, m2.y);
        m = max16(m);
        const float nms = -m * SCALE;
        const f32x2 M2 = {nms, nms};
        f32x2 s2 = {0.f, 0.f};
#pragma unroll
        for (int j = 0; j < 4; ++j) {
            f32x2 g = pk_fma(E[i][j], S2, M2);
            f32x2 e; e.x = __builtin_amdgcn_exp2f(g.x); e.y = __builtin_amdgcn_exp2f(g.y);
            E[i][j] = e;
            s2 = pk_add(s2, e);
        }
        float s = s2.x + s2.y;
        s = sum16(s);
        a[i] = __builtin_amdgcn_rcpf(s);   // s in [1,128]
    }

    // cross-wave col partials, double-buffered; split-quad layout -> 2-way banks (free)
    __shared__ float4 part[2][4][32];
    int pb = 0;

#pragma unroll 1
    for (int it = 0; it < NIT; ++it) {
        // ---- col phase: b_j = 1 / sum_i E_ij * a_i ----
        f32x2 sc[4];
#pragma unroll
        for (int j = 0; j < 4; ++j) sc[j] = (f32x2){0.f, 0.f};
#pragma unroll
        for (int i = 0; i < 8; ++i) {
            const f32x2 ai2 = {a[i], a[i]};
#pragma unroll
            for (int j = 0; j < 4; ++j) sc[j] = pk_fma(E[i][j], ai2, sc[j]);
        }
#pragma unroll
        for (int j = 0; j < 4; ++j) {      // reduce over 4 row-groups in wave (DS pipe)
            sc[j] = pk_add(sc[j], shflxor2(sc[j], 16));
            sc[j] = pk_add(sc[j], shflxor2(sc[j], 32));
        }
        if ((t & 63) < 16) {
            part[pb][wv][t & 15]        = make_float4(sc[0].x, sc[0].y, sc[1].x, sc[1].y);
            part[pb][wv][16 + (t & 15)] = make_float4(sc[2].x, sc[2].y, sc[3].x, sc[3].y);
        }
        __syncthreads();
        {
            float4 q0 = part[pb][0][cg];
            float4 q1 = part[pb][0][16 + cg];
            f32x2 t0 = {q0.x, q0.y}, t1 = {q0.z, q0.w};
            f32x2 t2 = {q1.x, q1.y}, t3 = {q1.z, q1.w};
#pragma unroll
            for (int w = 1; w < 4; ++w) {
                float4 r0 = part[pb][w][cg];
                float4 r1 = part[pb][w][16 + cg];
                t0 = pk_add(t0, (f32x2){r0.x, r0.y});
                t1 = pk_add(t1, (f32x2){r0.z, r0.w});
                t2 = pk_add(t2, (f32x2){r1.x, r1.y});
                t3 = pk_add(t3, (f32x2){r1.z, r1.w});
            }
            b[0].x = __builtin_amdgcn_rcpf(fmaxf(t0.x, SMIN));
            b[0].y = __builtin_amdgcn_rcpf(fmaxf(t0.y, SMIN));
            b[1].x = __builtin_amdgcn_rcpf(fmaxf(t1.x, SMIN));
            b[1].y = __builtin_amdgcn_rcpf(fmaxf(t1.y, SMIN));
            b[2].x = __builtin_amdgcn_rcpf(fmaxf(t2.x, SMIN));
            b[2].y = __builtin_amdgcn_rcpf(fmaxf(t2.y, SMIN));
            b[3].x = __builtin_amdgcn_rcpf(fmaxf(t3.x, SMIN));
            b[3].y = __builtin_amdgcn_rcpf(fmaxf(t3.y, SMIN));
        }
        pb ^= 1;

        // ---- row phase: a_i = 1 / sum_j E_ij * b_j  (skipped after the 21st col) ----
        if (it < NIT - 1) {
#pragma unroll
            for (int i = 0; i < 8; ++i) {
                f32x2 s2 = {0.f, 0.f};
#pragma unroll
                for (int j = 0; j < 4; ++j) s2 = pk_fma(E[i][j], b[j], s2);
                float s = s2.x + s2.y;
                s = sum16(s);
                a[i] = __builtin_amdgcn_rcpf(fmaxf(s, SMIN));
            }
        }
    }

    // ---- epilogue: out = E * a_i * b_j ----
#pragma unroll
    for (int i = 0; i < 8; ++i) {
        const f32x2 ai2 = {a[i], a[i]};
        f32x2 p0 = pk_mul(pk_mul(E[i][0], ai2), b[0]);
        f32x2 p1 = pk_mul(pk_mul(E[i][1], ai2), b[1]);
        f32x2 p2 = pk_mul(pk_mul(E[i][2], ai2), b[2]);
        f32x2 p3 = pk_mul(pk_mul(E[i][3], ai2), b[3]);
        *(float4*)(dst + (i << 7))     = make_float4(p0.x, p0.y, p1.x, p1.y);
        *(float4*)(dst + (i << 7) + 4) = make_float4(p2.x, p2.y, p3.x, p3.y);
    }
}

extern "C" void kernel_launch(void* const* d_in, const int* in_sizes, int n_in,
                              void* d_out, int out_size, void* d_ws, size_t ws_size,
                              hipStream_t stream) {
    (void)n_in; (void)d_ws; (void)ws_size; (void)out_size;
    const float* in  = (const float*)d_in[0];
    float*       out = (float*)d_out;
    const int n_mat = in_sizes[0] / (128 * 128);  // 4096
    sinkhorn_kernel<<<dim3(n_mat), dim3(256), 0, stream>>>(in, out);
}